// Round 2
// baseline (1898.883 us; speedup 1.0000x reference)
//
#include <hip/hip_runtime.h>
#include <hip/hip_bf16.h>
#include <math.h>

// ---------------------------------------------------------------------------
// MambaModel fused forward, fp32, ws-adaptive batch chunking.
// B=4096, S=9, d=256, H=2, hd=128, di=512, N=16, dtr=16, dcv=4
// Chunk arena layout (per-row float offsets, rows = nb*9):
//   [0,256)    h / h2
//   [256,1024) qkv   ; later aa=[256,512), f1=[512,768), f2=[768,1024)
//              mamba: xm=[256,768) -> dt/y=[256,768), xc=[768,1280)
//   [1024,1280) ao
//   [1280,1328) xdb ; later t32=[1280,1312)
// total 1328 floats/row.
// ---------------------------------------------------------------------------

#define BATCH 4096

// ---------------- embed: h = x * w1 + b1 -----------------------------------
__global__ __launch_bounds__(256) void embed_kernel(
    const float* __restrict__ x, const float* __restrict__ w1,
    const float* __restrict__ b1, float* __restrict__ h, int r0, int nr)
{
    int i = blockIdx.x * 256 + threadIdx.x;   // over nr*256
    if (i >= nr * 256) return;
    int c  = i & 255;
    int row = i >> 8;
    h[i] = x[r0 + row] * w1[c] + b1[c];
}

// ---------------- generic SGEMM: C = A(M,K;lda) @ W(N,K)^T + bias ----------
// act: 0 none, 1 relu, 2 softplus, 3 silu-gate (C *= silu(result))
__global__ __launch_bounds__(256) void sgemm_kernel(
    const float* __restrict__ A, const float* __restrict__ W,
    const float* __restrict__ bias, float* __restrict__ C,
    int M, int N, int K, int lda, int act)
{
    __shared__ float As[16][68];
    __shared__ float Ws[16][68];
    const int tid = threadIdx.x;
    const int m0 = blockIdx.y * 64;
    const int n0 = blockIdx.x * 64;
    const int tm = tid >> 4;      // 0..15
    const int tn = tid & 15;      // 0..15
    const int lrow = tid >> 2;    // 0..63
    const int lk   = (tid & 3) * 4;

    float acc[4][4] = {};

    for (int k0 = 0; k0 < K; k0 += 16) {
        {
            int m = m0 + lrow;
            float4 v = make_float4(0.f, 0.f, 0.f, 0.f);
            if (m < M) v = *reinterpret_cast<const float4*>(&A[(size_t)m * lda + k0 + lk]);
            As[lk + 0][lrow] = v.x; As[lk + 1][lrow] = v.y;
            As[lk + 2][lrow] = v.z; As[lk + 3][lrow] = v.w;
            int n = n0 + lrow;
            float4 w = make_float4(0.f, 0.f, 0.f, 0.f);
            if (n < N) w = *reinterpret_cast<const float4*>(&W[(size_t)n * K + k0 + lk]);
            Ws[lk + 0][lrow] = w.x; Ws[lk + 1][lrow] = w.y;
            Ws[lk + 2][lrow] = w.z; Ws[lk + 3][lrow] = w.w;
        }
        __syncthreads();
        #pragma unroll
        for (int k = 0; k < 16; ++k) {
            float4 av = *reinterpret_cast<const float4*>(&As[k][tm * 4]);
            float4 wv = *reinterpret_cast<const float4*>(&Ws[k][tn * 4]);
            float a[4] = {av.x, av.y, av.z, av.w};
            float w[4] = {wv.x, wv.y, wv.z, wv.w};
            #pragma unroll
            for (int i = 0; i < 4; ++i)
                #pragma unroll
                for (int j = 0; j < 4; ++j)
                    acc[i][j] = fmaf(a[i], w[j], acc[i][j]);
        }
        __syncthreads();
    }

    #pragma unroll
    for (int i = 0; i < 4; ++i) {
        int m = m0 + tm * 4 + i;
        if (m >= M) continue;
        #pragma unroll
        for (int j = 0; j < 4; ++j) {
            int n = n0 + tn * 4 + j;
            if (n >= N) continue;
            float v = acc[i][j];
            if (bias) v += bias[n];
            size_t idx = (size_t)m * N + n;
            if (act == 1) v = fmaxf(v, 0.f);
            else if (act == 2) v = (v > 20.f) ? v : log1pf(expf(v));
            else if (act == 3) {
                float sig = 1.f / (1.f + expf(-v));
                C[idx] = C[idx] * (v * sig);
                continue;
            }
            C[idx] = v;
        }
    }
}

// ---------------- attention per (b_local, head): S=9, hd=128 ---------------
__global__ __launch_bounds__(128) void attn_kernel(
    const float* __restrict__ qkv, float* __restrict__ o, int nb)
{
    __shared__ float q[9][132], kk[9][132], v[9][132];
    __shared__ float sc[9][12];
    const int blk = blockIdx.x;
    if (blk >= nb * 2) return;
    const int b = blk >> 1, head = blk & 1;
    const int t = threadIdx.x;
    const size_t base = (size_t)b * 9 * 768 + (size_t)head * 128;
    #pragma unroll
    for (int s = 0; s < 9; ++s) {
        q[s][t]  = qkv[base + s * 768 + t];
        kk[s][t] = qkv[base + s * 768 + 256 + t];
        v[s][t]  = qkv[base + s * 768 + 512 + t];
    }
    __syncthreads();
    if (t < 81) {
        int qi = t / 9, ki = t % 9;
        float acc = 0.f;
        #pragma unroll 8
        for (int c = 0; c < 128; ++c) acc = fmaf(q[qi][c], kk[ki][c], acc);
        sc[qi][ki] = acc * 0.08838834764831845f;  // 1/sqrt(128)
    }
    __syncthreads();
    if (t < 9) {
        float mx = -1e30f;
        #pragma unroll
        for (int k2 = 0; k2 < 9; ++k2) mx = fmaxf(mx, sc[t][k2]);
        float e[9], sum = 0.f;
        #pragma unroll
        for (int k2 = 0; k2 < 9; ++k2) { e[k2] = expf(sc[t][k2] - mx); sum += e[k2]; }
        float inv = 1.f / sum;
        #pragma unroll
        for (int k2 = 0; k2 < 9; ++k2) sc[t][k2] = e[k2] * inv;
    }
    __syncthreads();
    #pragma unroll
    for (int qi = 0; qi < 9; ++qi) {
        float acc = 0.f;
        #pragma unroll
        for (int k2 = 0; k2 < 9; ++k2) acc = fmaf(sc[qi][k2], v[k2][t], acc);
        o[(size_t)(b * 9 + qi) * 256 + head * 128 + t] = acc;
    }
}

// ---------------- residual add + LayerNorm, wave per row -------------------
__global__ __launch_bounds__(256) void ln_add_kernel(
    const float* __restrict__ h, const float* __restrict__ a,
    const float* __restrict__ g, const float* __restrict__ bb,
    float* __restrict__ out, int nrows)
{
    const int wave = threadIdx.x >> 6;
    const int lane = threadIdx.x & 63;
    const int row = blockIdx.x * 4 + wave;
    if (row >= nrows) return;
    const float4 hv = reinterpret_cast<const float4*>(h + (size_t)row * 256)[lane];
    const float4 av = reinterpret_cast<const float4*>(a + (size_t)row * 256)[lane];
    float x0 = hv.x + av.x, x1 = hv.y + av.y, x2 = hv.z + av.z, x3 = hv.w + av.w;
    float s  = x0 + x1 + x2 + x3;
    float sq = x0 * x0 + x1 * x1 + x2 * x2 + x3 * x3;
    #pragma unroll
    for (int off = 32; off; off >>= 1) {
        s  += __shfl_down(s, off);
        sq += __shfl_down(sq, off);
    }
    s = __shfl(s, 0); sq = __shfl(sq, 0);
    const float mean = s * (1.f / 256.f);
    const float var  = sq * (1.f / 256.f) - mean * mean;
    const float inv  = rsqrtf(var + 1e-5f);
    const float4 gv = reinterpret_cast<const float4*>(g)[lane];
    const float4 bv = reinterpret_cast<const float4*>(bb)[lane];
    float4 ov;
    ov.x = (x0 - mean) * inv * gv.x + bv.x;
    ov.y = (x1 - mean) * inv * gv.y + bv.y;
    ov.z = (x2 - mean) * inv * gv.z + bv.z;
    ov.w = (x3 - mean) * inv * gv.w + bv.w;
    reinterpret_cast<float4*>(out + (size_t)row * 256)[lane] = ov;
}

// ---------------- causal depthwise conv (w=4) + silu -----------------------
// xm: (nr,512) local rows; s = row % 9
__global__ __launch_bounds__(256) void conv_silu_kernel(
    const float* __restrict__ xm, const float* __restrict__ cw,
    const float* __restrict__ cb, float* __restrict__ xc, int nr)
{
    int i = blockIdx.x * 256 + threadIdx.x;  // nr*512
    if (i >= nr * 512) return;
    int c = i & 511;
    int bs = i >> 9;
    int s = bs % 9, b = bs / 9;
    float acc = cb[c];
    #pragma unroll
    for (int k = 0; k < 4; ++k) {
        int sp = s + k - 3;
        if (sp >= 0) acc = fmaf(cw[c * 4 + k], xm[(size_t)(b * 9 + sp) * 512 + c], acc);
    }
    float sig = 1.f / (1.f + expf(-acc));
    xc[(size_t)bs * 512 + c] = acc * sig;
}

// ---------------- SSM scan: thread per (b_local,c), 16 states in regs ------
// y = sum_n(h_n * C_n) + D*xc   (z-gating applied later by gemm epilogue)
__global__ __launch_bounds__(256) void scan_kernel(
    const float* __restrict__ dt, const float* __restrict__ xc,
    const float* __restrict__ xdb, const float* __restrict__ A_log,
    const float* __restrict__ Dp, float* __restrict__ y, int nb)
{
    int i = blockIdx.x * 256 + threadIdx.x;  // nb*512
    if (i >= nb * 512) return;
    int c = i & 511, b = i >> 9;
    float Ar[16];
    #pragma unroll
    for (int n = 0; n < 16; ++n) Ar[n] = -expf(A_log[c * 16 + n]);
    float hst[16] = {};
    const float Dc = Dp[c];
    for (int s = 0; s < 9; ++s) {
        size_t bs = (size_t)(b * 9 + s);
        float dtv = dt[bs * 512 + c];
        float xv  = xc[bs * 512 + c];
        const float* xb = xdb + bs * 48;
        float acc = 0.f;
        #pragma unroll
        for (int n = 0; n < 16; ++n) {
            hst[n] = hst[n] * expf(dtv * Ar[n]) + dtv * xb[16 + n] * xv;
            acc = fmaf(hst[n], xb[32 + n], acc);
        }
        y[bs * 512 + c] = acc + Dc * xv;
    }
}

// ---------------- final head: (nr,32) -> (nb,9) -> out[b0+b] ---------------
__global__ __launch_bounds__(256) void head_kernel(
    const float* __restrict__ t32, const float* __restrict__ w2b,
    const float* __restrict__ b2b, const float* __restrict__ w3a,
    const float* __restrict__ b3a, const float* __restrict__ w3b,
    const float* __restrict__ b3b, float* __restrict__ out, int b0, int nb)
{
    int b = blockIdx.x * 256 + threadIdx.x;
    if (b >= nb) return;
    float o9[9];
    #pragma unroll
    for (int s = 0; s < 9; ++s) {
        const float* r = t32 + (size_t)(b * 9 + s) * 32;
        float acc = b2b[0];
        #pragma unroll
        for (int k = 0; k < 32; ++k) acc = fmaf(r[k], w2b[k], acc);
        o9[s] = acc;
    }
    float accout = b3b[0];
    #pragma unroll
    for (int j = 0; j < 9; ++j) {
        float rj = b3a[j];
        #pragma unroll
        for (int s = 0; s < 9; ++s) rj = fmaf(o9[s], w3a[j * 9 + s], rj);
        rj = fmaxf(rj, 0.f);
        accout = fmaf(rj, w3b[j], accout);
    }
    out[b0 + b] = accout;
}

// ---------------------------------------------------------------------------
extern "C" void kernel_launch(void* const* d_in, const int* in_sizes, int n_in,
                              void* d_out, int out_size, void* d_ws, size_t ws_size,
                              hipStream_t stream)
{
    const float* x          = (const float*)d_in[0];
    const float* w1         = (const float*)d_in[1];
    const float* b1         = (const float*)d_in[2];
    const float* attn_in_w  = (const float*)d_in[3];
    const float* attn_in_b  = (const float*)d_in[4];
    const float* attn_out_w = (const float*)d_in[5];
    const float* attn_out_b = (const float*)d_in[6];
    const float* ln1_g      = (const float*)d_in[7];
    const float* ln1_b      = (const float*)d_in[8];
    const float* ffw_w1     = (const float*)d_in[9];
    const float* ffw_b1     = (const float*)d_in[10];
    const float* ffw_w2     = (const float*)d_in[11];
    const float* ffw_b2     = (const float*)d_in[12];
    const float* ln2_g      = (const float*)d_in[13];
    const float* ln2_b      = (const float*)d_in[14];
    const float* in_proj_w  = (const float*)d_in[15];
    const float* conv_w     = (const float*)d_in[16];
    const float* conv_b     = (const float*)d_in[17];
    const float* x_proj_w   = (const float*)d_in[18];
    const float* dt_proj_w  = (const float*)d_in[19];
    const float* dt_proj_b  = (const float*)d_in[20];
    const float* A_log      = (const float*)d_in[21];
    const float* Dp         = (const float*)d_in[22];
    const float* out_proj_w = (const float*)d_in[23];
    const float* w2a        = (const float*)d_in[24];
    const float* b2a        = (const float*)d_in[25];
    const float* w2b        = (const float*)d_in[26];
    const float* b2b        = (const float*)d_in[27];
    const float* w3a        = (const float*)d_in[28];
    const float* b3a        = (const float*)d_in[29];
    const float* w3b        = (const float*)d_in[30];
    const float* b3b        = (const float*)d_in[31];
    float* out = (float*)d_out;

    // ---- choose chunk count so arena fits in ws_size (constant per session)
    const size_t PER_ROW = 1328;   // floats per token row
    int nchunks = 1;
    while (nchunks < 32 &&
           (size_t)(BATCH / nchunks) * 9 * PER_ROW * sizeof(float) > ws_size)
        nchunks <<= 1;
    const int nb = BATCH / nchunks;
    const int nr = nb * 9;
    const size_t CAPR = (size_t)nr;

    float* ws = (float*)d_ws;

    auto gemm = [&](const float* A, const float* W, const float* bias, float* C,
                    int M, int N, int K, int lda, int act) {
        dim3 grid((N + 63) / 64, (M + 63) / 64);
        hipLaunchKernelGGL(sgemm_kernel, grid, dim3(256), 0, stream,
                           A, W, bias, C, M, N, K, lda, act);
    };

    for (int ck = 0; ck < nchunks; ++ck) {
        const int b0 = ck * nb;
        const int r0 = b0 * 9;

        float* h    = ws;                   // [0,256)
        float* qkv  = ws + CAPR * 256;      // [256,1024)
        float* ao   = ws + CAPR * 1024;     // [1024,1280)
        float* aa   = ws + CAPR * 256;      // [256,512)   (qkv dead)
        float* f1   = ws + CAPR * 512;      // [512,768)
        float* f2   = ws + CAPR * 768;      // [768,1024)
        float* xm   = ws + CAPR * 256;      // [256,768)
        float* xc   = ws + CAPR * 768;      // [768,1280)
        float* xdb  = ws + CAPR * 1280;     // [1280,1328)
        float* dty  = ws + CAPR * 256;      // [256,768)   dt then y
        float* h2   = ws;                   // [0,256)
        float* t32  = ws + CAPR * 1280;     // [1280,1312)

        hipLaunchKernelGGL(embed_kernel, dim3((nr * 256 + 255) / 256), dim3(256),
                           0, stream, x, w1, b1, h, r0, nr);

        for (int i = 0; i < 2; ++i) {
            gemm(h, attn_in_w + (size_t)i * 768 * 256, attn_in_b + i * 768, qkv,
                 nr, 768, 256, 256, 0);
            hipLaunchKernelGGL(attn_kernel, dim3(nb * 2), dim3(128), 0, stream,
                               qkv, ao, nb);
            gemm(ao, attn_out_w + (size_t)i * 256 * 256, attn_out_b + i * 256, aa,
                 nr, 256, 256, 256, 0);
            hipLaunchKernelGGL(ln_add_kernel, dim3((nr + 3) / 4), dim3(256), 0, stream,
                               h, aa, ln1_g + i * 256, ln1_b + i * 256, h, nr);
            gemm(h, ffw_w1 + (size_t)i * 256 * 256, ffw_b1 + i * 256, f1,
                 nr, 256, 256, 256, 1);
            gemm(f1, ffw_w2 + (size_t)i * 256 * 256, ffw_b2 + i * 256, f2,
                 nr, 256, 256, 256, 0);
            hipLaunchKernelGGL(ln_add_kernel, dim3((nr + 3) / 4), dim3(256), 0, stream,
                               h, f2, ln2_g + i * 256, ln2_b + i * 256, h, nr);
        }

        // Mamba block
        gemm(h, in_proj_w, nullptr, xm, nr, 512, 256, 256, 0);           // xm half
        hipLaunchKernelGGL(conv_silu_kernel, dim3((nr * 512 + 255) / 256), dim3(256),
                           0, stream, xm, conv_w, conv_b, xc, nr);
        gemm(xc, x_proj_w, nullptr, xdb, nr, 48, 512, 512, 0);
        gemm(xdb, dt_proj_w, dt_proj_b, dty, nr, 512, 16, 48, 2);        // softplus
        hipLaunchKernelGGL(scan_kernel, dim3((nb * 512 + 255) / 256), dim3(256),
                           0, stream, dty, xc, xdb, A_log, Dp, dty, nb); // dt -> y in place
        // z-gemm with silu-gate epilogue: y *= silu(h @ in_proj_w[512:].T)
        gemm(h, in_proj_w + (size_t)512 * 256, nullptr, dty, nr, 512, 256, 256, 3);
        gemm(dty, out_proj_w, nullptr, h2, nr, 256, 512, 512, 0);
        gemm(h2, w2a, b2a, t32, nr, 32, 256, 256, 0);
        hipLaunchKernelGGL(head_kernel, dim3((nb + 255) / 256), dim3(256), 0, stream,
                           t32, w2b, b2b, w3a, b3a, w3b, b3b, out, b0, nb);
    }
}

// Round 4
// 1189.730 us; speedup vs baseline: 1.5961x; 1.5961x over previous
//
#include <hip/hip_runtime.h>
#include <hip/hip_bf16.h>
#include <math.h>

// ---------------------------------------------------------------------------
// MambaModel fused forward. Big GEMMs on bf16 MFMA (fp32 accum), rest fp32.
// B=4096, S=9, d=256, H=2, hd=128, di=512, N=16, dtr=16, dcv=4
// ---------------------------------------------------------------------------

#define BATCH 4096

typedef __attribute__((ext_vector_type(8))) short short8;
typedef __attribute__((ext_vector_type(4))) float f32x4;
typedef __attribute__((ext_vector_type(2))) unsigned int u32x2;

__device__ __forceinline__ unsigned f2bf(float f) {
    unsigned u = __float_as_uint(f);
    u += 0x7fffu + ((u >> 16) & 1u);   // RNE to bf16
    return u >> 16;
}

// ---------------- embed: h = x * w1 + b1 -----------------------------------
__global__ __launch_bounds__(256) void embed_kernel(
    const float* __restrict__ x, const float* __restrict__ w1,
    const float* __restrict__ b1, float* __restrict__ h, int r0, int nr)
{
    int i = blockIdx.x * 256 + threadIdx.x;
    if (i >= nr * 256) return;
    int c  = i & 255;
    int row = i >> 8;
    h[i] = x[r0 + row] * w1[c] + b1[c];
}

// ---------------- MFMA GEMM: C = A(M,K;lda) @ W(N,K)^T + bias --------------
// M%128==0, N%128==0, K%64==0. act: 0 none, 1 relu, 3 silu-gate (C *= silu(v))
__global__ __launch_bounds__(256) void mgemm_kernel(
    const float* __restrict__ A, const float* __restrict__ W,
    const float* __restrict__ bias, float* __restrict__ C,
    int M, int N, int K, int lda, int act)
{
    __shared__ unsigned short As[128 * 64];   // bf16 bits, [row][k] + XOR swizzle
    __shared__ unsigned short Bs[128 * 64];

    const int tid  = threadIdx.x;
    const int m0   = blockIdx.x * 128;
    const int n0   = blockIdx.y * 128;
    const int wid  = tid >> 6, lane = tid & 63;
    const int wr   = wid >> 1, wc = wid & 1;        // wave -> 64x64 quadrant
    const int lrow = lane & 15, lk8 = lane >> 4, l7 = lane & 7;
    const int trow = tid >> 4, tchk = tid & 15;     // staging: 16 thr/row

    f32x4 acc[4][4];
    #pragma unroll
    for (int i = 0; i < 4; ++i)
        #pragma unroll
        for (int j = 0; j < 4; ++j)
            acc[i][j] = f32x4{0.f, 0.f, 0.f, 0.f};

    for (int k0 = 0; k0 < K; k0 += 64) {
        // ---- stage 128x64 fp32 -> bf16 LDS for A and W, swizzled ----------
        #pragma unroll
        for (int p = 0; p < 8; ++p) {
            const int r = p * 16 + trow;
            const float4 av = *reinterpret_cast<const float4*>(
                &A[(size_t)(m0 + r) * lda + k0 + tchk * 4]);
            const float4 wv = *reinterpret_cast<const float4*>(
                &W[(size_t)(n0 + r) * K + k0 + tchk * 4]);
            const int off = r * 64 + (((tchk >> 1) ^ (r & 7)) << 3) + (tchk & 1) * 4;
            u32x2 ap, wp;
            ap.x = f2bf(av.x) | (f2bf(av.y) << 16);
            ap.y = f2bf(av.z) | (f2bf(av.w) << 16);
            wp.x = f2bf(wv.x) | (f2bf(wv.y) << 16);
            wp.y = f2bf(wv.z) | (f2bf(wv.w) << 16);
            *reinterpret_cast<u32x2*>(&As[off]) = ap;
            *reinterpret_cast<u32x2*>(&Bs[off]) = wp;
        }
        __syncthreads();

        // ---- 2 k-halves x (4x4) MFMA -------------------------------------
        #pragma unroll
        for (int kh = 0; kh < 2; ++kh) {
            short8 af[4], bf[4];
            #pragma unroll
            for (int i = 0; i < 4; ++i) {
                const int ra = wr * 64 + i * 16 + lrow;
                const int rb = wc * 64 + i * 16 + lrow;
                const int sl = ((kh << 2) | lk8) ^ l7;   // row&7 == lane&7
                af[i] = *reinterpret_cast<const short8*>(&As[ra * 64 + sl * 8]);
                bf[i] = *reinterpret_cast<const short8*>(&Bs[rb * 64 + sl * 8]);
            }
            #pragma unroll
            for (int i = 0; i < 4; ++i)
                #pragma unroll
                for (int j = 0; j < 4; ++j)
                    acc[i][j] = __builtin_amdgcn_mfma_f32_16x16x32_bf16(
                        af[i], bf[j], acc[i][j], 0, 0, 0);
        }
        __syncthreads();
    }

    // ---- epilogue: C layout col=lane&15, row=(lane>>4)*4+reg --------------
    const int cb = n0 + wc * 64 + lrow;
    const int rb = m0 + wr * 64 + lk8 * 4;
    float bj[4];
    #pragma unroll
    for (int j = 0; j < 4; ++j) bj[j] = bias ? bias[cb + j * 16] : 0.f;

    #pragma unroll
    for (int i = 0; i < 4; ++i) {
        #pragma unroll
        for (int r = 0; r < 4; ++r) {
            const size_t mrow = (size_t)(rb + i * 16 + r) * N;
            #pragma unroll
            for (int j = 0; j < 4; ++j) {
                float v = acc[i][j][r] + bj[j];
                const size_t idx = mrow + cb + j * 16;
                if (act == 1) v = fmaxf(v, 0.f);
                else if (act == 3) {
                    const float sig = 1.f / (1.f + expf(-v));
                    C[idx] = C[idx] * (v * sig);
                    continue;
                }
                C[idx] = v;
            }
        }
    }
}

// ---------------- fp32 SGEMM for small/odd shapes --------------------------
// act: 0 none, 1 relu, 2 softplus
__global__ __launch_bounds__(256) void sgemm_kernel(
    const float* __restrict__ A, const float* __restrict__ W,
    const float* __restrict__ bias, float* __restrict__ C,
    int M, int N, int K, int lda, int act)
{
    __shared__ float As[16][68];
    __shared__ float Ws[16][68];
    const int tid = threadIdx.x;
    const int m0 = blockIdx.y * 64;
    const int n0 = blockIdx.x * 64;
    const int tm = tid >> 4;
    const int tn = tid & 15;
    const int lrow = tid >> 2;
    const int lk   = (tid & 3) * 4;

    float acc[4][4] = {};

    for (int k0 = 0; k0 < K; k0 += 16) {
        {
            int m = m0 + lrow;
            float4 v = make_float4(0.f, 0.f, 0.f, 0.f);
            if (m < M) v = *reinterpret_cast<const float4*>(&A[(size_t)m * lda + k0 + lk]);
            As[lk + 0][lrow] = v.x; As[lk + 1][lrow] = v.y;
            As[lk + 2][lrow] = v.z; As[lk + 3][lrow] = v.w;
            int n = n0 + lrow;
            float4 w = make_float4(0.f, 0.f, 0.f, 0.f);
            if (n < N) w = *reinterpret_cast<const float4*>(&W[(size_t)n * K + k0 + lk]);
            Ws[lk + 0][lrow] = w.x; Ws[lk + 1][lrow] = w.y;
            Ws[lk + 2][lrow] = w.z; Ws[lk + 3][lrow] = w.w;
        }
        __syncthreads();
        #pragma unroll
        for (int k = 0; k < 16; ++k) {
            float4 av = *reinterpret_cast<const float4*>(&As[k][tm * 4]);
            float4 wv = *reinterpret_cast<const float4*>(&Ws[k][tn * 4]);
            float a[4] = {av.x, av.y, av.z, av.w};
            float w[4] = {wv.x, wv.y, wv.z, wv.w};
            #pragma unroll
            for (int i = 0; i < 4; ++i)
                #pragma unroll
                for (int j = 0; j < 4; ++j)
                    acc[i][j] = fmaf(a[i], w[j], acc[i][j]);
        }
        __syncthreads();
    }

    #pragma unroll
    for (int i = 0; i < 4; ++i) {
        int m = m0 + tm * 4 + i;
        if (m >= M) continue;
        #pragma unroll
        for (int j = 0; j < 4; ++j) {
            int n = n0 + tn * 4 + j;
            if (n >= N) continue;
            float v = acc[i][j];
            if (bias) v += bias[n];
            if (act == 1) v = fmaxf(v, 0.f);
            else if (act == 2) v = (v > 20.f) ? v : log1pf(expf(v));
            C[(size_t)m * N + n] = v;
        }
    }
}

// ---------------- attention per (b_local, head): S=9, hd=128 ---------------
__global__ __launch_bounds__(128) void attn_kernel(
    const float* __restrict__ qkv, float* __restrict__ o, int nb)
{
    __shared__ float q[9][132], kk[9][132], v[9][132];
    __shared__ float sc[9][12];
    const int blk = blockIdx.x;
    if (blk >= nb * 2) return;
    const int b = blk >> 1, head = blk & 1;
    const int t = threadIdx.x;
    const size_t base = (size_t)b * 9 * 768 + (size_t)head * 128;
    #pragma unroll
    for (int s = 0; s < 9; ++s) {
        q[s][t]  = qkv[base + s * 768 + t];
        kk[s][t] = qkv[base + s * 768 + 256 + t];
        v[s][t]  = qkv[base + s * 768 + 512 + t];
    }
    __syncthreads();
    if (t < 81) {
        int qi = t / 9, ki = t % 9;
        float acc = 0.f;
        #pragma unroll 8
        for (int c = 0; c < 128; ++c) acc = fmaf(q[qi][c], kk[ki][c], acc);
        sc[qi][ki] = acc * 0.08838834764831845f;
    }
    __syncthreads();
    if (t < 9) {
        float mx = -1e30f;
        #pragma unroll
        for (int k2 = 0; k2 < 9; ++k2) mx = fmaxf(mx, sc[t][k2]);
        float e[9], sum = 0.f;
        #pragma unroll
        for (int k2 = 0; k2 < 9; ++k2) { e[k2] = expf(sc[t][k2] - mx); sum += e[k2]; }
        float inv = 1.f / sum;
        #pragma unroll
        for (int k2 = 0; k2 < 9; ++k2) sc[t][k2] = e[k2] * inv;
    }
    __syncthreads();
    #pragma unroll
    for (int qi = 0; qi < 9; ++qi) {
        float acc = 0.f;
        #pragma unroll
        for (int k2 = 0; k2 < 9; ++k2) acc = fmaf(sc[qi][k2], v[k2][t], acc);
        o[(size_t)(b * 9 + qi) * 256 + head * 128 + t] = acc;
    }
}

// ---------------- residual add + LayerNorm, wave per row -------------------
__global__ __launch_bounds__(256) void ln_add_kernel(
    const float* __restrict__ h, const float* __restrict__ a,
    const float* __restrict__ g, const float* __restrict__ bb,
    float* __restrict__ out, int nrows)
{
    const int wave = threadIdx.x >> 6;
    const int lane = threadIdx.x & 63;
    const int row = blockIdx.x * 4 + wave;
    if (row >= nrows) return;
    const float4 hv = reinterpret_cast<const float4*>(h + (size_t)row * 256)[lane];
    const float4 av = reinterpret_cast<const float4*>(a + (size_t)row * 256)[lane];
    float x0 = hv.x + av.x, x1 = hv.y + av.y, x2 = hv.z + av.z, x3 = hv.w + av.w;
    float s  = x0 + x1 + x2 + x3;
    float sq = x0 * x0 + x1 * x1 + x2 * x2 + x3 * x3;
    #pragma unroll
    for (int off = 32; off; off >>= 1) {
        s  += __shfl_down(s, off);
        sq += __shfl_down(sq, off);
    }
    s = __shfl(s, 0); sq = __shfl(sq, 0);
    const float mean = s * (1.f / 256.f);
    const float var  = sq * (1.f / 256.f) - mean * mean;
    const float inv  = rsqrtf(var + 1e-5f);
    const float4 gv = reinterpret_cast<const float4*>(g)[lane];
    const float4 bv = reinterpret_cast<const float4*>(bb)[lane];
    float4 ov;
    ov.x = (x0 - mean) * inv * gv.x + bv.x;
    ov.y = (x1 - mean) * inv * gv.y + bv.y;
    ov.z = (x2 - mean) * inv * gv.z + bv.z;
    ov.w = (x3 - mean) * inv * gv.w + bv.w;
    reinterpret_cast<float4*>(out + (size_t)row * 256)[lane] = ov;
}

// ---------------- causal depthwise conv (w=4) + silu -----------------------
__global__ __launch_bounds__(256) void conv_silu_kernel(
    const float* __restrict__ xm, const float* __restrict__ cw,
    const float* __restrict__ cb, float* __restrict__ xc, int nr)
{
    int i = blockIdx.x * 256 + threadIdx.x;
    if (i >= nr * 512) return;
    int c = i & 511;
    int bs = i >> 9;
    int s = bs % 9, b = bs / 9;
    float acc = cb[c];
    #pragma unroll
    for (int k = 0; k < 4; ++k) {
        int sp = s + k - 3;
        if (sp >= 0) acc = fmaf(cw[c * 4 + k], xm[(size_t)(b * 9 + sp) * 512 + c], acc);
    }
    float sig = 1.f / (1.f + expf(-acc));
    xc[(size_t)bs * 512 + c] = acc * sig;
}

// ---------------- SSM scan: thread per (b_local,c), 16 states in regs ------
__global__ __launch_bounds__(256) void scan_kernel(
    const float* __restrict__ dt, const float* __restrict__ xc,
    const float* __restrict__ xdb, const float* __restrict__ A_log,
    const float* __restrict__ Dp, float* __restrict__ y, int nb)
{
    int i = blockIdx.x * 256 + threadIdx.x;
    if (i >= nb * 512) return;
    int c = i & 511, b = i >> 9;
    float Ar[16];
    #pragma unroll
    for (int n = 0; n < 16; ++n) Ar[n] = -expf(A_log[c * 16 + n]);
    float hst[16] = {};
    const float Dc = Dp[c];
    for (int s = 0; s < 9; ++s) {
        size_t bs = (size_t)(b * 9 + s);
        float dtv = dt[bs * 512 + c];
        float xv  = xc[bs * 512 + c];
        const float* xb = xdb + bs * 48;
        float acc = 0.f;
        #pragma unroll
        for (int n = 0; n < 16; ++n) {
            hst[n] = hst[n] * expf(dtv * Ar[n]) + dtv * xb[16 + n] * xv;
            acc = fmaf(hst[n], xb[32 + n], acc);
        }
        y[bs * 512 + c] = acc + Dc * xv;
    }
}

// ---------------- final head: (nr,32) -> (nb,9) -> out[b0+b] ---------------
__global__ __launch_bounds__(256) void head_kernel(
    const float* __restrict__ t32, const float* __restrict__ w2b,
    const float* __restrict__ b2b, const float* __restrict__ w3a,
    const float* __restrict__ b3a, const float* __restrict__ w3b,
    const float* __restrict__ b3b, float* __restrict__ out, int b0, int nb)
{
    int b = blockIdx.x * 256 + threadIdx.x;
    if (b >= nb) return;
    float o9[9];
    #pragma unroll
    for (int s = 0; s < 9; ++s) {
        const float* r = t32 + (size_t)(b * 9 + s) * 32;
        float acc = b2b[0];
        #pragma unroll
        for (int k = 0; k < 32; ++k) acc = fmaf(r[k], w2b[k], acc);
        o9[s] = acc;
    }
    float accout = b3b[0];
    #pragma unroll
    for (int j = 0; j < 9; ++j) {
        float rj = b3a[j];
        #pragma unroll
        for (int s = 0; s < 9; ++s) rj = fmaf(o9[s], w3a[j * 9 + s], rj);
        rj = fmaxf(rj, 0.f);
        accout = fmaf(rj, w3b[j], accout);
    }
    out[b0 + b] = accout;
}

// ---------------------------------------------------------------------------
extern "C" void kernel_launch(void* const* d_in, const int* in_sizes, int n_in,
                              void* d_out, int out_size, void* d_ws, size_t ws_size,
                              hipStream_t stream)
{
    const float* x          = (const float*)d_in[0];
    const float* w1         = (const float*)d_in[1];
    const float* b1         = (const float*)d_in[2];
    const float* attn_in_w  = (const float*)d_in[3];
    const float* attn_in_b  = (const float*)d_in[4];
    const float* attn_out_w = (const float*)d_in[5];
    const float* attn_out_b = (const float*)d_in[6];
    const float* ln1_g      = (const float*)d_in[7];
    const float* ln1_b      = (const float*)d_in[8];
    const float* ffw_w1     = (const float*)d_in[9];
    const float* ffw_b1     = (const float*)d_in[10];
    const float* ffw_w2     = (const float*)d_in[11];
    const float* ffw_b2     = (const float*)d_in[12];
    const float* ln2_g      = (const float*)d_in[13];
    const float* ln2_b      = (const float*)d_in[14];
    const float* in_proj_w  = (const float*)d_in[15];
    const float* conv_w     = (const float*)d_in[16];
    const float* conv_b     = (const float*)d_in[17];
    const float* x_proj_w   = (const float*)d_in[18];
    const float* dt_proj_w  = (const float*)d_in[19];
    const float* dt_proj_b  = (const float*)d_in[20];
    const float* A_log      = (const float*)d_in[21];
    const float* Dp         = (const float*)d_in[22];
    const float* out_proj_w = (const float*)d_in[23];
    const float* w2a        = (const float*)d_in[24];
    const float* b2a        = (const float*)d_in[25];
    const float* w2b        = (const float*)d_in[26];
    const float* b2b        = (const float*)d_in[27];
    const float* w3a        = (const float*)d_in[28];
    const float* b3a        = (const float*)d_in[29];
    const float* w3b        = (const float*)d_in[30];
    const float* b3b        = (const float*)d_in[31];
    float* out = (float*)d_out;

    const size_t PER_ROW = 1328;
    int nchunks = 1;
    while (nchunks < 32 &&
           (size_t)(BATCH / nchunks) * 9 * PER_ROW * sizeof(float) > ws_size)
        nchunks <<= 1;
    const int nb = BATCH / nchunks;
    const int nr = nb * 9;
    const size_t CAPR = (size_t)nr;

    float* ws = (float*)d_ws;

    auto gemm = [&](const float* A, const float* W, const float* bias, float* C,
                    int M, int N, int K, int lda, int act) {
        dim3 grid((N + 63) / 64, (M + 63) / 64);
        hipLaunchKernelGGL(sgemm_kernel, grid, dim3(256), 0, stream,
                           A, W, bias, C, M, N, K, lda, act);
    };
    auto mgemm = [&](const float* A, const float* W, const float* bias, float* C,
                     int M, int N, int K, int lda, int act) {
        dim3 grid(M / 128, N / 128);
        hipLaunchKernelGGL(mgemm_kernel, grid, dim3(256), 0, stream,
                           A, W, bias, C, M, N, K, lda, act);
    };

    for (int ck = 0; ck < nchunks; ++ck) {
        const int b0 = ck * nb;
        const int r0 = b0 * 9;

        float* h    = ws;                   // [0,256)
        float* qkv  = ws + CAPR * 256;      // [256,1024)
        float* ao   = ws + CAPR * 1024;     // [1024,1280)
        float* aa   = ws + CAPR * 256;      // [256,512)
        float* f1   = ws + CAPR * 512;      // [512,768)
        float* f2   = ws + CAPR * 768;      // [768,1024)
        float* xm   = ws + CAPR * 256;      // [256,768)
        float* xc   = ws + CAPR * 768;      // [768,1280)
        float* xdb  = ws + CAPR * 1280;     // [1280,1328)
        float* dty  = ws + CAPR * 256;      // [256,768)
        float* h2   = ws;                   // [0,256)
        float* t32  = ws + CAPR * 1280;     // [1280,1312)

        hipLaunchKernelGGL(embed_kernel, dim3((nr * 256 + 255) / 256), dim3(256),
                           0, stream, x, w1, b1, h, r0, nr);

        for (int i = 0; i < 2; ++i) {
            mgemm(h, attn_in_w + (size_t)i * 768 * 256, attn_in_b + i * 768, qkv,
                  nr, 768, 256, 256, 0);
            hipLaunchKernelGGL(attn_kernel, dim3(nb * 2), dim3(128), 0, stream,
                               qkv, ao, nb);
            mgemm(ao, attn_out_w + (size_t)i * 256 * 256, attn_out_b + i * 256, aa,
                  nr, 256, 256, 256, 0);
            hipLaunchKernelGGL(ln_add_kernel, dim3((nr + 3) / 4), dim3(256), 0, stream,
                               h, aa, ln1_g + i * 256, ln1_b + i * 256, h, nr);
            mgemm(h, ffw_w1 + (size_t)i * 256 * 256, ffw_b1 + i * 256, f1,
                  nr, 256, 256, 256, 1);
            mgemm(f1, ffw_w2 + (size_t)i * 256 * 256, ffw_b2 + i * 256, f2,
                  nr, 256, 256, 256, 0);
            hipLaunchKernelGGL(ln_add_kernel, dim3((nr + 3) / 4), dim3(256), 0, stream,
                               h, f2, ln2_g + i * 256, ln2_b + i * 256, h, nr);
        }

        // Mamba block
        mgemm(h, in_proj_w, nullptr, xm, nr, 512, 256, 256, 0);
        hipLaunchKernelGGL(conv_silu_kernel, dim3((nr * 512 + 255) / 256), dim3(256),
                           0, stream, xm, conv_w, conv_b, xc, nr);
        gemm(xc, x_proj_w, nullptr, xdb, nr, 48, 512, 512, 0);
        gemm(xdb, dt_proj_w, dt_proj_b, dty, nr, 512, 16, 48, 2);
        hipLaunchKernelGGL(scan_kernel, dim3((nb * 512 + 255) / 256), dim3(256),
                           0, stream, dty, xc, xdb, A_log, Dp, dty, nb);
        mgemm(h, in_proj_w + (size_t)512 * 256, nullptr, dty, nr, 512, 256, 256, 3);
        mgemm(dty, out_proj_w, nullptr, h2, nr, 256, 512, 512, 0);
        gemm(h2, w2a, b2a, t32, nr, 32, 256, 256, 0);
        hipLaunchKernelGGL(head_kernel, dim3((nb + 255) / 256), dim3(256), 0, stream,
                           t32, w2b, b2b, w3a, b3a, w3b, b3b, out, b0, nb);
    }
}

// Round 5
// 1054.801 us; speedup vs baseline: 1.8002x; 1.1279x over previous
//
#include <hip/hip_runtime.h>
#include <hip/hip_bf16.h>
#include <math.h>

// ---------------------------------------------------------------------------
// MambaModel fused forward. Big GEMMs on bf16 MFMA (fp32 accum), rest fp32.
// B=4096, S=9, d=256, H=2, hd=128, di=512, N=16, dtr=16, dcv=4
// R4: scan uses __expf + fused dt_proj/softplus + fused z-silu gating.
// ---------------------------------------------------------------------------

#define BATCH 4096

typedef __attribute__((ext_vector_type(8))) short short8;
typedef __attribute__((ext_vector_type(4))) float f32x4;
typedef __attribute__((ext_vector_type(2))) unsigned int u32x2;

__device__ __forceinline__ unsigned f2bf(float f) {
    unsigned u = __float_as_uint(f);
    u += 0x7fffu + ((u >> 16) & 1u);   // RNE to bf16
    return u >> 16;
}

// ---------------- embed: h = x * w1 + b1 -----------------------------------
__global__ __launch_bounds__(256) void embed_kernel(
    const float* __restrict__ x, const float* __restrict__ w1,
    const float* __restrict__ b1, float* __restrict__ h, int r0, int nr)
{
    int i = blockIdx.x * 256 + threadIdx.x;
    if (i >= nr * 256) return;
    int c  = i & 255;
    int row = i >> 8;
    h[i] = x[r0 + row] * w1[c] + b1[c];
}

// ---------------- MFMA GEMM: C = A(M,K;lda) @ W(N,K)^T + bias --------------
// M%128==0, N%128==0, K%64==0. act: 0 none, 1 relu
__global__ __launch_bounds__(256) void mgemm_kernel(
    const float* __restrict__ A, const float* __restrict__ W,
    const float* __restrict__ bias, float* __restrict__ C,
    int M, int N, int K, int lda, int act)
{
    __shared__ unsigned short As[128 * 64];   // bf16 bits, [row][k] + XOR swizzle
    __shared__ unsigned short Bs[128 * 64];

    const int tid  = threadIdx.x;
    const int m0   = blockIdx.x * 128;
    const int n0   = blockIdx.y * 128;
    const int wid  = tid >> 6, lane = tid & 63;
    const int wr   = wid >> 1, wc = wid & 1;        // wave -> 64x64 quadrant
    const int lrow = lane & 15, lk8 = lane >> 4, l7 = lane & 7;
    const int trow = tid >> 4, tchk = tid & 15;     // staging: 16 thr/row

    f32x4 acc[4][4];
    #pragma unroll
    for (int i = 0; i < 4; ++i)
        #pragma unroll
        for (int j = 0; j < 4; ++j)
            acc[i][j] = f32x4{0.f, 0.f, 0.f, 0.f};

    for (int k0 = 0; k0 < K; k0 += 64) {
        // ---- stage 128x64 fp32 -> bf16 LDS for A and W, swizzled ----------
        #pragma unroll
        for (int p = 0; p < 8; ++p) {
            const int r = p * 16 + trow;
            const float4 av = *reinterpret_cast<const float4*>(
                &A[(size_t)(m0 + r) * lda + k0 + tchk * 4]);
            const float4 wv = *reinterpret_cast<const float4*>(
                &W[(size_t)(n0 + r) * K + k0 + tchk * 4]);
            const int off = r * 64 + (((tchk >> 1) ^ (r & 7)) << 3) + (tchk & 1) * 4;
            u32x2 ap, wp;
            ap.x = f2bf(av.x) | (f2bf(av.y) << 16);
            ap.y = f2bf(av.z) | (f2bf(av.w) << 16);
            wp.x = f2bf(wv.x) | (f2bf(wv.y) << 16);
            wp.y = f2bf(wv.z) | (f2bf(wv.w) << 16);
            *reinterpret_cast<u32x2*>(&As[off]) = ap;
            *reinterpret_cast<u32x2*>(&Bs[off]) = wp;
        }
        __syncthreads();

        // ---- 2 k-halves x (4x4) MFMA -------------------------------------
        #pragma unroll
        for (int kh = 0; kh < 2; ++kh) {
            short8 af[4], bf[4];
            #pragma unroll
            for (int i = 0; i < 4; ++i) {
                const int ra = wr * 64 + i * 16 + lrow;
                const int rb = wc * 64 + i * 16 + lrow;
                const int sl = ((kh << 2) | lk8) ^ l7;   // row&7 == lane&7
                af[i] = *reinterpret_cast<const short8*>(&As[ra * 64 + sl * 8]);
                bf[i] = *reinterpret_cast<const short8*>(&Bs[rb * 64 + sl * 8]);
            }
            #pragma unroll
            for (int i = 0; i < 4; ++i)
                #pragma unroll
                for (int j = 0; j < 4; ++j)
                    acc[i][j] = __builtin_amdgcn_mfma_f32_16x16x32_bf16(
                        af[i], bf[j], acc[i][j], 0, 0, 0);
        }
        __syncthreads();
    }

    // ---- epilogue: C layout col=lane&15, row=(lane>>4)*4+reg --------------
    const int cb = n0 + wc * 64 + lrow;
    const int rb = m0 + wr * 64 + lk8 * 4;
    float bj[4];
    #pragma unroll
    for (int j = 0; j < 4; ++j) bj[j] = bias ? bias[cb + j * 16] : 0.f;

    #pragma unroll
    for (int i = 0; i < 4; ++i) {
        #pragma unroll
        for (int r = 0; r < 4; ++r) {
            const size_t mrow = (size_t)(rb + i * 16 + r) * N;
            #pragma unroll
            for (int j = 0; j < 4; ++j) {
                float v = acc[i][j][r] + bj[j];
                if (act == 1) v = fmaxf(v, 0.f);
                C[mrow + cb + j * 16] = v;
            }
        }
    }
}

// ---------------- fp32 SGEMM for small/odd shapes --------------------------
// act: 0 none, 1 relu
__global__ __launch_bounds__(256) void sgemm_kernel(
    const float* __restrict__ A, const float* __restrict__ W,
    const float* __restrict__ bias, float* __restrict__ C,
    int M, int N, int K, int lda, int act)
{
    __shared__ float As[16][68];
    __shared__ float Ws[16][68];
    const int tid = threadIdx.x;
    const int m0 = blockIdx.y * 64;
    const int n0 = blockIdx.x * 64;
    const int tm = tid >> 4;
    const int tn = tid & 15;
    const int lrow = tid >> 2;
    const int lk   = (tid & 3) * 4;

    float acc[4][4] = {};

    for (int k0 = 0; k0 < K; k0 += 16) {
        {
            int m = m0 + lrow;
            float4 v = make_float4(0.f, 0.f, 0.f, 0.f);
            if (m < M) v = *reinterpret_cast<const float4*>(&A[(size_t)m * lda + k0 + lk]);
            As[lk + 0][lrow] = v.x; As[lk + 1][lrow] = v.y;
            As[lk + 2][lrow] = v.z; As[lk + 3][lrow] = v.w;
            int n = n0 + lrow;
            float4 w = make_float4(0.f, 0.f, 0.f, 0.f);
            if (n < N) w = *reinterpret_cast<const float4*>(&W[(size_t)n * K + k0 + lk]);
            Ws[lk + 0][lrow] = w.x; Ws[lk + 1][lrow] = w.y;
            Ws[lk + 2][lrow] = w.z; Ws[lk + 3][lrow] = w.w;
        }
        __syncthreads();
        #pragma unroll
        for (int k = 0; k < 16; ++k) {
            float4 av = *reinterpret_cast<const float4*>(&As[k][tm * 4]);
            float4 wv = *reinterpret_cast<const float4*>(&Ws[k][tn * 4]);
            float a[4] = {av.x, av.y, av.z, av.w};
            float w[4] = {wv.x, wv.y, wv.z, wv.w};
            #pragma unroll
            for (int i = 0; i < 4; ++i)
                #pragma unroll
                for (int j = 0; j < 4; ++j)
                    acc[i][j] = fmaf(a[i], w[j], acc[i][j]);
        }
        __syncthreads();
    }

    #pragma unroll
    for (int i = 0; i < 4; ++i) {
        int m = m0 + tm * 4 + i;
        if (m >= M) continue;
        #pragma unroll
        for (int j = 0; j < 4; ++j) {
            int n = n0 + tn * 4 + j;
            if (n >= N) continue;
            float v = acc[i][j];
            if (bias) v += bias[n];
            if (act == 1) v = fmaxf(v, 0.f);
            C[(size_t)m * N + n] = v;
        }
    }
}

// ---------------- attention per (b_local, head): S=9, hd=128 ---------------
__global__ __launch_bounds__(128) void attn_kernel(
    const float* __restrict__ qkv, float* __restrict__ o, int nb)
{
    __shared__ float q[9][132], kk[9][132], v[9][132];
    __shared__ float sc[9][12];
    const int blk = blockIdx.x;
    if (blk >= nb * 2) return;
    const int b = blk >> 1, head = blk & 1;
    const int t = threadIdx.x;
    const size_t base = (size_t)b * 9 * 768 + (size_t)head * 128;
    #pragma unroll
    for (int s = 0; s < 9; ++s) {
        q[s][t]  = qkv[base + s * 768 + t];
        kk[s][t] = qkv[base + s * 768 + 256 + t];
        v[s][t]  = qkv[base + s * 768 + 512 + t];
    }
    __syncthreads();
    if (t < 81) {
        int qi = t / 9, ki = t % 9;
        float acc = 0.f;
        #pragma unroll 8
        for (int c = 0; c < 128; ++c) acc = fmaf(q[qi][c], kk[ki][c], acc);
        sc[qi][ki] = acc * 0.08838834764831845f;
    }
    __syncthreads();
    if (t < 9) {
        float mx = -1e30f;
        #pragma unroll
        for (int k2 = 0; k2 < 9; ++k2) mx = fmaxf(mx, sc[t][k2]);
        float e[9], sum = 0.f;
        #pragma unroll
        for (int k2 = 0; k2 < 9; ++k2) { e[k2] = __expf(sc[t][k2] - mx); sum += e[k2]; }
        float inv = 1.f / sum;
        #pragma unroll
        for (int k2 = 0; k2 < 9; ++k2) sc[t][k2] = e[k2] * inv;
    }
    __syncthreads();
    #pragma unroll
    for (int qi = 0; qi < 9; ++qi) {
        float acc = 0.f;
        #pragma unroll
        for (int k2 = 0; k2 < 9; ++k2) acc = fmaf(sc[qi][k2], v[k2][t], acc);
        o[(size_t)(b * 9 + qi) * 256 + head * 128 + t] = acc;
    }
}

// ---------------- residual add + LayerNorm, wave per row -------------------
__global__ __launch_bounds__(256) void ln_add_kernel(
    const float* __restrict__ h, const float* __restrict__ a,
    const float* __restrict__ g, const float* __restrict__ bb,
    float* __restrict__ out, int nrows)
{
    const int wave = threadIdx.x >> 6;
    const int lane = threadIdx.x & 63;
    const int row = blockIdx.x * 4 + wave;
    if (row >= nrows) return;
    const float4 hv = reinterpret_cast<const float4*>(h + (size_t)row * 256)[lane];
    const float4 av = reinterpret_cast<const float4*>(a + (size_t)row * 256)[lane];
    float x0 = hv.x + av.x, x1 = hv.y + av.y, x2 = hv.z + av.z, x3 = hv.w + av.w;
    float s  = x0 + x1 + x2 + x3;
    float sq = x0 * x0 + x1 * x1 + x2 * x2 + x3 * x3;
    #pragma unroll
    for (int off = 32; off; off >>= 1) {
        s  += __shfl_down(s, off);
        sq += __shfl_down(sq, off);
    }
    s = __shfl(s, 0); sq = __shfl(sq, 0);
    const float mean = s * (1.f / 256.f);
    const float var  = sq * (1.f / 256.f) - mean * mean;
    const float inv  = rsqrtf(var + 1e-5f);
    const float4 gv = reinterpret_cast<const float4*>(g)[lane];
    const float4 bv = reinterpret_cast<const float4*>(bb)[lane];
    float4 ov;
    ov.x = (x0 - mean) * inv * gv.x + bv.x;
    ov.y = (x1 - mean) * inv * gv.y + bv.y;
    ov.z = (x2 - mean) * inv * gv.z + bv.z;
    ov.w = (x3 - mean) * inv * gv.w + bv.w;
    reinterpret_cast<float4*>(out + (size_t)row * 256)[lane] = ov;
}

// ---------------- causal depthwise conv (w=4) + silu -----------------------
__global__ __launch_bounds__(256) void conv_silu_kernel(
    const float* __restrict__ xm, const float* __restrict__ cw,
    const float* __restrict__ cb, float* __restrict__ xc, int nr)
{
    int i = blockIdx.x * 256 + threadIdx.x;
    if (i >= nr * 512) return;
    int c = i & 511;
    int bs = i >> 9;
    int s = bs % 9, b = bs / 9;
    float acc = cb[c];
    #pragma unroll
    for (int k = 0; k < 4; ++k) {
        int sp = s + k - 3;
        if (sp >= 0) acc = fmaf(cw[c * 4 + k], xm[(size_t)(b * 9 + sp) * 512 + c], acc);
    }
    float sig = 1.f / (1.f + __expf(-acc));
    xc[(size_t)bs * 512 + c] = acc * sig;
}

// ---------------- SSM scan: thread per (b_local,c), fused dt_proj+gate -----
// Reads xc, xdb; computes dt = softplus(xdb[:16]@wdt + dtb); runs recurrence;
// reads z from zy and writes y*silu(z) back into zy in place.
__global__ __launch_bounds__(256) void scan_kernel(
    const float* __restrict__ xc, const float* __restrict__ xdb,
    const float* __restrict__ dt_w, const float* __restrict__ dt_b,
    const float* __restrict__ A_log, const float* __restrict__ Dp,
    float* __restrict__ zy, int nb)
{
    int i = blockIdx.x * 256 + threadIdx.x;
    if (i >= nb * 512) return;
    int c = i & 511, b = i >> 9;

    float wdt[16], Ar[16];
    #pragma unroll
    for (int n = 0; n < 16; n += 4) {
        float4 wv = *reinterpret_cast<const float4*>(&dt_w[c * 16 + n]);
        wdt[n] = wv.x; wdt[n + 1] = wv.y; wdt[n + 2] = wv.z; wdt[n + 3] = wv.w;
        float4 av = *reinterpret_cast<const float4*>(&A_log[c * 16 + n]);
        Ar[n] = -__expf(av.x); Ar[n + 1] = -__expf(av.y);
        Ar[n + 2] = -__expf(av.z); Ar[n + 3] = -__expf(av.w);
    }
    const float dtb = dt_b[c];
    const float Dc  = Dp[c];

    float hst[16] = {};
    for (int s = 0; s < 9; ++s) {
        const size_t bs = (size_t)(b * 9 + s);
        const float* xb = xdb + bs * 48;
        float dti = dtb;
        #pragma unroll
        for (int n = 0; n < 16; ++n) dti = fmaf(xb[n], wdt[n], dti);
        const float dt = (dti > 20.f) ? dti : log1pf(__expf(dti));
        const float xv = xc[bs * 512 + c];
        const float dtx = dt * xv;
        float acc = 0.f;
        #pragma unroll
        for (int n = 0; n < 16; ++n) {
            hst[n] = fmaf(hst[n], __expf(dt * Ar[n]), dtx * xb[16 + n]);
            acc = fmaf(hst[n], xb[32 + n], acc);
        }
        const float z = zy[bs * 512 + c];
        const float sig = 1.f / (1.f + __expf(-z));
        zy[bs * 512 + c] = (acc + Dc * xv) * (z * sig);
    }
}

// ---------------- final head: (nr,32) -> (nb,9) -> out[b0+b] ---------------
__global__ __launch_bounds__(256) void head_kernel(
    const float* __restrict__ t32, const float* __restrict__ w2b,
    const float* __restrict__ b2b, const float* __restrict__ w3a,
    const float* __restrict__ b3a, const float* __restrict__ w3b,
    const float* __restrict__ b3b, float* __restrict__ out, int b0, int nb)
{
    int b = blockIdx.x * 256 + threadIdx.x;
    if (b >= nb) return;
    float o9[9];
    #pragma unroll
    for (int s = 0; s < 9; ++s) {
        const float* r = t32 + (size_t)(b * 9 + s) * 32;
        float acc = b2b[0];
        #pragma unroll
        for (int k = 0; k < 32; ++k) acc = fmaf(r[k], w2b[k], acc);
        o9[s] = acc;
    }
    float accout = b3b[0];
    #pragma unroll
    for (int j = 0; j < 9; ++j) {
        float rj = b3a[j];
        #pragma unroll
        for (int s = 0; s < 9; ++s) rj = fmaf(o9[s], w3a[j * 9 + s], rj);
        rj = fmaxf(rj, 0.f);
        accout = fmaf(rj, w3b[j], accout);
    }
    out[b0 + b] = accout;
}

// ---------------------------------------------------------------------------
extern "C" void kernel_launch(void* const* d_in, const int* in_sizes, int n_in,
                              void* d_out, int out_size, void* d_ws, size_t ws_size,
                              hipStream_t stream)
{
    const float* x          = (const float*)d_in[0];
    const float* w1         = (const float*)d_in[1];
    const float* b1         = (const float*)d_in[2];
    const float* attn_in_w  = (const float*)d_in[3];
    const float* attn_in_b  = (const float*)d_in[4];
    const float* attn_out_w = (const float*)d_in[5];
    const float* attn_out_b = (const float*)d_in[6];
    const float* ln1_g      = (const float*)d_in[7];
    const float* ln1_b      = (const float*)d_in[8];
    const float* ffw_w1     = (const float*)d_in[9];
    const float* ffw_b1     = (const float*)d_in[10];
    const float* ffw_w2     = (const float*)d_in[11];
    const float* ffw_b2     = (const float*)d_in[12];
    const float* ln2_g      = (const float*)d_in[13];
    const float* ln2_b      = (const float*)d_in[14];
    const float* in_proj_w  = (const float*)d_in[15];
    const float* conv_w     = (const float*)d_in[16];
    const float* conv_b     = (const float*)d_in[17];
    const float* x_proj_w   = (const float*)d_in[18];
    const float* dt_proj_w  = (const float*)d_in[19];
    const float* dt_proj_b  = (const float*)d_in[20];
    const float* A_log      = (const float*)d_in[21];
    const float* Dp         = (const float*)d_in[22];
    const float* out_proj_w = (const float*)d_in[23];
    const float* w2a        = (const float*)d_in[24];
    const float* b2a        = (const float*)d_in[25];
    const float* w2b        = (const float*)d_in[26];
    const float* b2b        = (const float*)d_in[27];
    const float* w3a        = (const float*)d_in[28];
    const float* b3a        = (const float*)d_in[29];
    const float* w3b        = (const float*)d_in[30];
    const float* b3b        = (const float*)d_in[31];
    float* out = (float*)d_out;

    const size_t PER_ROW = 1328;
    int nchunks = 1;
    while (nchunks < 32 &&
           (size_t)(BATCH / nchunks) * 9 * PER_ROW * sizeof(float) > ws_size)
        nchunks <<= 1;
    const int nb = BATCH / nchunks;
    const int nr = nb * 9;
    const size_t CAPR = (size_t)nr;

    float* ws = (float*)d_ws;

    auto gemm = [&](const float* A, const float* W, const float* bias, float* C,
                    int M, int N, int K, int lda, int act) {
        dim3 grid((N + 63) / 64, (M + 63) / 64);
        hipLaunchKernelGGL(sgemm_kernel, grid, dim3(256), 0, stream,
                           A, W, bias, C, M, N, K, lda, act);
    };
    auto mgemm = [&](const float* A, const float* W, const float* bias, float* C,
                     int M, int N, int K, int lda, int act) {
        dim3 grid(M / 128, N / 128);
        hipLaunchKernelGGL(mgemm_kernel, grid, dim3(256), 0, stream,
                           A, W, bias, C, M, N, K, lda, act);
    };

    for (int ck = 0; ck < nchunks; ++ck) {
        const int b0 = ck * nb;
        const int r0 = b0 * 9;

        float* h    = ws;                   // [0,256)
        float* qkv  = ws + CAPR * 256;      // [256,1024)
        float* ao   = ws + CAPR * 1024;     // [1024,1280)
        float* aa   = ws + CAPR * 256;      // [256,512)
        float* f1   = ws + CAPR * 512;      // [512,768)
        float* f2   = ws + CAPR * 768;      // [768,1024)
        float* xm   = ws + CAPR * 256;      // [256,768)
        float* xc   = ws + CAPR * 768;      // [768,1280)
        float* xdb  = ws + CAPR * 1280;     // [1280,1328)
        float* zy   = ws + CAPR * 256;      // [256,768)  z then gated y (in place)
        float* h2   = ws;                   // [0,256)
        float* t32  = ws + CAPR * 1280;     // [1280,1312)

        hipLaunchKernelGGL(embed_kernel, dim3((nr * 256 + 255) / 256), dim3(256),
                           0, stream, x, w1, b1, h, r0, nr);

        for (int i = 0; i < 2; ++i) {
            mgemm(h, attn_in_w + (size_t)i * 768 * 256, attn_in_b + i * 768, qkv,
                  nr, 768, 256, 256, 0);
            hipLaunchKernelGGL(attn_kernel, dim3(nb * 2), dim3(128), 0, stream,
                               qkv, ao, nb);
            mgemm(ao, attn_out_w + (size_t)i * 256 * 256, attn_out_b + i * 256, aa,
                  nr, 256, 256, 256, 0);
            hipLaunchKernelGGL(ln_add_kernel, dim3((nr + 3) / 4), dim3(256), 0, stream,
                               h, aa, ln1_g + i * 256, ln1_b + i * 256, h, nr);
            mgemm(h, ffw_w1 + (size_t)i * 256 * 256, ffw_b1 + i * 256, f1,
                  nr, 256, 256, 256, 1);
            mgemm(f1, ffw_w2 + (size_t)i * 256 * 256, ffw_b2 + i * 256, f2,
                  nr, 256, 256, 256, 0);
            hipLaunchKernelGGL(ln_add_kernel, dim3((nr + 3) / 4), dim3(256), 0, stream,
                               h, f2, ln2_g + i * 256, ln2_b + i * 256, h, nr);
        }

        // Mamba block
        mgemm(h, in_proj_w, nullptr, xm, nr, 512, 256, 256, 0);      // xm
        hipLaunchKernelGGL(conv_silu_kernel, dim3((nr * 512 + 255) / 256), dim3(256),
                           0, stream, xm, conv_w, conv_b, xc, nr);
        gemm(xc, x_proj_w, nullptr, xdb, nr, 48, 512, 512, 0);
        mgemm(h, in_proj_w + (size_t)512 * 256, nullptr, zy, nr, 512, 256, 256, 0); // z (xm dead)
        hipLaunchKernelGGL(scan_kernel, dim3((nb * 512 + 255) / 256), dim3(256),
                           0, stream, xc, xdb, dt_proj_w, dt_proj_b, A_log, Dp, zy, nb);
        mgemm(zy, out_proj_w, nullptr, h2, nr, 256, 512, 512, 0);
        gemm(h2, w2a, b2a, t32, nr, 32, 256, 256, 0);
        hipLaunchKernelGGL(head_kernel, dim3((nb + 255) / 256), dim3(256), 0, stream,
                           t32, w2b, b2b, w3a, b3a, w3b, b3b, out, b0, nb);
    }
}

// Round 6
// 791.215 us; speedup vs baseline: 2.4000x; 1.3331x over previous
//
#include <hip/hip_runtime.h>
#include <hip/hip_bf16.h>
#include <math.h>

// ---------------------------------------------------------------------------
// MambaModel fused forward. All big GEMMs: bf16 MFMA with PRE-CONVERTED bf16
// operands (weights once per launch; activations written bf16 by producers).
// B=4096, S=9, d=256, H=2, hd=128, di=512, N=16, dtr=16, dcv=4
// Arena (float units x CAPR): h@0(256) hbf@256(128) aux@384(128) big@512(768)
//   xc@1280(512). Weights bf16 arena: ws[0..589824) floats (1179648 ushorts).
// ---------------------------------------------------------------------------

#define BATCH 4096

typedef __attribute__((ext_vector_type(8))) short short8;
typedef __attribute__((ext_vector_type(4))) float f32x4;
typedef __attribute__((ext_vector_type(4))) unsigned short u16x4;
typedef unsigned short ushort;

__device__ __forceinline__ ushort f2bf(float f) {
    unsigned u = __float_as_uint(f);
    u += 0x7fffu + ((u >> 16) & 1u);   // RNE to bf16
    return (ushort)(u >> 16);
}

// ---------------- one-shot weight conversion fp32 -> bf16 ------------------
// segments (sizes): attn_in 393216 | attn_out 131072 | ffw1 131072 |
//                   ffw2 131072 | in_proj 262144 | out_proj 131072
__global__ __launch_bounds__(256) void convw_kernel(
    const float* __restrict__ s0, const float* __restrict__ s1,
    const float* __restrict__ s2, const float* __restrict__ s3,
    const float* __restrict__ s4, const float* __restrict__ s5,
    ushort* __restrict__ dst)
{
    int i = blockIdx.x * 256 + threadIdx.x;
    float v;
    if      (i < 393216)  v = s0[i];
    else if (i < 524288)  v = s1[i - 393216];
    else if (i < 655360)  v = s2[i - 524288];
    else if (i < 786432)  v = s3[i - 655360];
    else if (i < 1048576) v = s4[i - 786432];
    else                  v = s5[i - 1048576];
    dst[i] = f2bf(v);
}

// ---------------- embed: h = x * w1 + b1 (fp32 + bf16 copy) ----------------
__global__ __launch_bounds__(256) void embed_kernel(
    const float* __restrict__ x, const float* __restrict__ w1,
    const float* __restrict__ b1, float* __restrict__ h,
    ushort* __restrict__ hbf, int r0, int nr)
{
    int i = blockIdx.x * 256 + threadIdx.x;
    if (i >= nr * 256) return;
    int c  = i & 255;
    int row = i >> 8;
    float v = x[r0 + row] * w1[c] + b1[c];
    h[i] = v;
    hbf[i] = f2bf(v);
}

// ---------------- MFMA GEMM, bf16 operands ---------------------------------
// A (M,K;lda) bf16, W (N,K) bf16. act: 0 none, 1 relu.
// outmode: 0 -> Cf fp32 ; 1 -> Cb bf16 ; 2 -> gate: Cb = bf16(yin * v*sig(v))
__global__ __launch_bounds__(256) void mgemm_kernel(
    const ushort* __restrict__ A, const ushort* __restrict__ W,
    const float* __restrict__ bias, float* __restrict__ Cf,
    ushort* __restrict__ Cb, const float* __restrict__ yin,
    int M, int N, int K, int lda, int act, int outmode)
{
    __shared__ ushort As[128 * 64];   // [row][k], 8-elt slots XOR-swizzled
    __shared__ ushort Bs[128 * 64];

    const int tid  = threadIdx.x;
    const int m0   = blockIdx.x * 128;
    const int n0   = blockIdx.y * 128;
    const int wid  = tid >> 6, lane = tid & 63;
    const int wr   = wid >> 1, wc = wid & 1;        // wave -> 64x64 quadrant
    const int lrow = lane & 15, lk8 = lane >> 4, l7 = lane & 7;
    const int trow = tid >> 3, tchk = tid & 7;      // staging: 8 thr/row

    f32x4 acc[4][4];
    #pragma unroll
    for (int i = 0; i < 4; ++i)
        #pragma unroll
        for (int j = 0; j < 4; ++j)
            acc[i][j] = f32x4{0.f, 0.f, 0.f, 0.f};

    for (int k0 = 0; k0 < K; k0 += 64) {
        // ---- stage 128x64 bf16 -> LDS, 16B units, slot ^= row&7 -----------
        #pragma unroll
        for (int p = 0; p < 4; ++p) {
            const int r = p * 32 + trow;
            const short8 av = *reinterpret_cast<const short8*>(
                &A[(size_t)(m0 + r) * lda + k0 + tchk * 8]);
            const short8 wv = *reinterpret_cast<const short8*>(
                &W[(size_t)(n0 + r) * K + k0 + tchk * 8]);
            const int off = r * 64 + ((tchk ^ (r & 7)) << 3);
            *reinterpret_cast<short8*>(&As[off]) = av;
            *reinterpret_cast<short8*>(&Bs[off]) = wv;
        }
        __syncthreads();

        // ---- 2 k-halves x (4x4) MFMA -------------------------------------
        #pragma unroll
        for (int kh = 0; kh < 2; ++kh) {
            short8 af[4], bf[4];
            #pragma unroll
            for (int i = 0; i < 4; ++i) {
                const int ra = wr * 64 + i * 16 + lrow;
                const int rb = wc * 64 + i * 16 + lrow;
                const int sl = ((kh << 2) | lk8) ^ l7;   // row&7 == lane&7
                af[i] = *reinterpret_cast<const short8*>(&As[ra * 64 + sl * 8]);
                bf[i] = *reinterpret_cast<const short8*>(&Bs[rb * 64 + sl * 8]);
            }
            #pragma unroll
            for (int i = 0; i < 4; ++i)
                #pragma unroll
                for (int j = 0; j < 4; ++j)
                    acc[i][j] = __builtin_amdgcn_mfma_f32_16x16x32_bf16(
                        af[i], bf[j], acc[i][j], 0, 0, 0);
        }
        __syncthreads();
    }

    // ---- epilogue: C layout col=lane&15, row=(lane>>4)*4+reg --------------
    const int cb = n0 + wc * 64 + lrow;
    const int rb = m0 + wr * 64 + lk8 * 4;
    float bj[4];
    #pragma unroll
    for (int j = 0; j < 4; ++j) bj[j] = bias ? bias[cb + j * 16] : 0.f;

    #pragma unroll
    for (int i = 0; i < 4; ++i) {
        #pragma unroll
        for (int r = 0; r < 4; ++r) {
            const size_t mrow = (size_t)(rb + i * 16 + r) * N;
            #pragma unroll
            for (int j = 0; j < 4; ++j) {
                float v = acc[i][j][r] + bj[j];
                const size_t idx = mrow + cb + j * 16;
                if (act == 1) v = fmaxf(v, 0.f);
                if (outmode == 0) {
                    Cf[idx] = v;
                } else if (outmode == 1) {
                    Cb[idx] = f2bf(v);
                } else {
                    const float sig = 1.f / (1.f + __expf(-v));
                    Cb[idx] = f2bf(yin[idx] * (v * sig));
                }
            }
        }
    }
}

// ---------------- fp32 SGEMM for small/odd shapes --------------------------
__global__ __launch_bounds__(256) void sgemm_kernel(
    const float* __restrict__ A, const float* __restrict__ W,
    const float* __restrict__ bias, float* __restrict__ C,
    int M, int N, int K, int lda, int act)
{
    __shared__ float As[16][68];
    __shared__ float Ws[16][68];
    const int tid = threadIdx.x;
    const int m0 = blockIdx.y * 64;
    const int n0 = blockIdx.x * 64;
    const int tm = tid >> 4;
    const int tn = tid & 15;
    const int lrow = tid >> 2;
    const int lk   = (tid & 3) * 4;

    float acc[4][4] = {};

    for (int k0 = 0; k0 < K; k0 += 16) {
        {
            int m = m0 + lrow;
            float4 v = make_float4(0.f, 0.f, 0.f, 0.f);
            if (m < M) v = *reinterpret_cast<const float4*>(&A[(size_t)m * lda + k0 + lk]);
            As[lk + 0][lrow] = v.x; As[lk + 1][lrow] = v.y;
            As[lk + 2][lrow] = v.z; As[lk + 3][lrow] = v.w;
            int n = n0 + lrow;
            float4 w = make_float4(0.f, 0.f, 0.f, 0.f);
            if (n < N) w = *reinterpret_cast<const float4*>(&W[(size_t)n * K + k0 + lk]);
            Ws[lk + 0][lrow] = w.x; Ws[lk + 1][lrow] = w.y;
            Ws[lk + 2][lrow] = w.z; Ws[lk + 3][lrow] = w.w;
        }
        __syncthreads();
        #pragma unroll
        for (int k = 0; k < 16; ++k) {
            float4 av = *reinterpret_cast<const float4*>(&As[k][tm * 4]);
            float4 wv = *reinterpret_cast<const float4*>(&Ws[k][tn * 4]);
            float a[4] = {av.x, av.y, av.z, av.w};
            float w[4] = {wv.x, wv.y, wv.z, wv.w};
            #pragma unroll
            for (int i = 0; i < 4; ++i)
                #pragma unroll
                for (int j = 0; j < 4; ++j)
                    acc[i][j] = fmaf(a[i], w[j], acc[i][j]);
        }
        __syncthreads();
    }

    #pragma unroll
    for (int i = 0; i < 4; ++i) {
        int m = m0 + tm * 4 + i;
        if (m >= M) continue;
        #pragma unroll
        for (int j = 0; j < 4; ++j) {
            int n = n0 + tn * 4 + j;
            if (n >= N) continue;
            float v = acc[i][j];
            if (bias) v += bias[n];
            if (act == 1) v = fmaxf(v, 0.f);
            C[(size_t)m * N + n] = v;
        }
    }
}

// ---------------- attention per (b_local, head): S=9, hd=128 ---------------
__global__ __launch_bounds__(128) void attn_kernel(
    const float* __restrict__ qkv, ushort* __restrict__ o, int nb)
{
    __shared__ float q[9][132], kk[9][132], v[9][132];
    __shared__ float sc[9][12];
    const int blk = blockIdx.x;
    if (blk >= nb * 2) return;
    const int b = blk >> 1, head = blk & 1;
    const int t = threadIdx.x;
    const size_t base = (size_t)b * 9 * 768 + (size_t)head * 128;
    #pragma unroll
    for (int s = 0; s < 9; ++s) {
        q[s][t]  = qkv[base + s * 768 + t];
        kk[s][t] = qkv[base + s * 768 + 256 + t];
        v[s][t]  = qkv[base + s * 768 + 512 + t];
    }
    __syncthreads();
    if (t < 81) {
        int qi = t / 9, ki = t % 9;
        float acc = 0.f;
        #pragma unroll 8
        for (int c = 0; c < 128; ++c) acc = fmaf(q[qi][c], kk[ki][c], acc);
        sc[qi][ki] = acc * 0.08838834764831845f;
    }
    __syncthreads();
    if (t < 9) {
        float mx = -1e30f;
        #pragma unroll
        for (int k2 = 0; k2 < 9; ++k2) mx = fmaxf(mx, sc[t][k2]);
        float e[9], sum = 0.f;
        #pragma unroll
        for (int k2 = 0; k2 < 9; ++k2) { e[k2] = __expf(sc[t][k2] - mx); sum += e[k2]; }
        float inv = 1.f / sum;
        #pragma unroll
        for (int k2 = 0; k2 < 9; ++k2) sc[t][k2] = e[k2] * inv;
    }
    __syncthreads();
    #pragma unroll
    for (int qi = 0; qi < 9; ++qi) {
        float acc = 0.f;
        #pragma unroll
        for (int k2 = 0; k2 < 9; ++k2) acc = fmaf(sc[qi][k2], v[k2][t], acc);
        o[(size_t)(b * 9 + qi) * 256 + head * 128 + t] = f2bf(acc);
    }
}

// ---------------- residual add + LayerNorm, wave per row -------------------
__global__ __launch_bounds__(256) void ln_add_kernel(
    const float* __restrict__ h, const float* __restrict__ a,
    const float* __restrict__ g, const float* __restrict__ bb,
    float* __restrict__ out, ushort* __restrict__ outbf, int nrows)
{
    const int wave = threadIdx.x >> 6;
    const int lane = threadIdx.x & 63;
    const int row = blockIdx.x * 4 + wave;
    if (row >= nrows) return;
    const float4 hv = reinterpret_cast<const float4*>(h + (size_t)row * 256)[lane];
    const float4 av = reinterpret_cast<const float4*>(a + (size_t)row * 256)[lane];
    float x0 = hv.x + av.x, x1 = hv.y + av.y, x2 = hv.z + av.z, x3 = hv.w + av.w;
    float s  = x0 + x1 + x2 + x3;
    float sq = x0 * x0 + x1 * x1 + x2 * x2 + x3 * x3;
    #pragma unroll
    for (int off = 32; off; off >>= 1) {
        s  += __shfl_down(s, off);
        sq += __shfl_down(sq, off);
    }
    s = __shfl(s, 0); sq = __shfl(sq, 0);
    const float mean = s * (1.f / 256.f);
    const float var  = sq * (1.f / 256.f) - mean * mean;
    const float inv  = rsqrtf(var + 1e-5f);
    const float4 gv = reinterpret_cast<const float4*>(g)[lane];
    const float4 bv = reinterpret_cast<const float4*>(bb)[lane];
    float4 ov;
    ov.x = (x0 - mean) * inv * gv.x + bv.x;
    ov.y = (x1 - mean) * inv * gv.y + bv.y;
    ov.z = (x2 - mean) * inv * gv.z + bv.z;
    ov.w = (x3 - mean) * inv * gv.w + bv.w;
    reinterpret_cast<float4*>(out + (size_t)row * 256)[lane] = ov;
    u16x4 bf;
    bf.x = f2bf(ov.x); bf.y = f2bf(ov.y); bf.z = f2bf(ov.z); bf.w = f2bf(ov.w);
    reinterpret_cast<u16x4*>(outbf + (size_t)row * 256)[lane] = bf;
}

// ---------------- causal depthwise conv (w=4) + silu -----------------------
__global__ __launch_bounds__(256) void conv_silu_kernel(
    const float* __restrict__ xm, const float* __restrict__ cw,
    const float* __restrict__ cb, float* __restrict__ xc, int nr)
{
    int i = blockIdx.x * 256 + threadIdx.x;
    if (i >= nr * 512) return;
    int c = i & 511;
    int bs = i >> 9;
    int s = bs % 9, b = bs / 9;
    float acc = cb[c];
    #pragma unroll
    for (int k = 0; k < 4; ++k) {
        int sp = s + k - 3;
        if (sp >= 0) acc = fmaf(cw[c * 4 + k], xm[(size_t)(b * 9 + sp) * 512 + c], acc);
    }
    float sig = 1.f / (1.f + __expf(-acc));
    xc[(size_t)bs * 512 + c] = acc * sig;
}

// ---------------- SSM scan: block per b (512 thr), xdb in LDS --------------
// y = sum_n(h_n*C_n) + D*xc written IN PLACE over xc. dt fused (softplus).
// Exploits A[n] ~= -(n+1) via exp-chain when detected (guarded, else general).
__global__ __launch_bounds__(512) void scan_kernel(
    float* __restrict__ xcy, const float* __restrict__ xdb,
    const float* __restrict__ dt_w, const float* __restrict__ dt_b,
    const float* __restrict__ A_log, const float* __restrict__ Dp)
{
    __shared__ float sx[9 * 48];
    const int c = threadIdx.x;
    const int b = blockIdx.x;
    if (c < 108) {
        reinterpret_cast<float4*>(sx)[c] =
            reinterpret_cast<const float4*>(xdb + (size_t)b * 432)[c];
    }

    float wdt[16], Ar[16];
    #pragma unroll
    for (int n = 0; n < 16; n += 4) {
        float4 wv = *reinterpret_cast<const float4*>(&dt_w[c * 16 + n]);
        wdt[n] = wv.x; wdt[n + 1] = wv.y; wdt[n + 2] = wv.z; wdt[n + 3] = wv.w;
        float4 av = *reinterpret_cast<const float4*>(&A_log[c * 16 + n]);
        Ar[n] = -__expf(av.x); Ar[n + 1] = -__expf(av.y);
        Ar[n + 2] = -__expf(av.z); Ar[n + 3] = -__expf(av.w);
    }
    const float dtb = dt_b[c];
    const float Dc  = Dp[c];
    const float a1  = Ar[0];
    bool chain = true;
    #pragma unroll
    for (int n = 1; n < 16; ++n)
        chain = chain && (fabsf(Ar[n] - (float)(n + 1) * a1) <=
                          1e-3f * (float)(n + 1) * fabsf(a1));
    __syncthreads();

    float hst[16] = {};
    for (int s = 0; s < 9; ++s) {
        const float* xb = sx + s * 48;
        float dti = dtb;
        #pragma unroll
        for (int n = 0; n < 16; ++n) dti = fmaf(xb[n], wdt[n], dti);
        const float dt = (dti > 20.f) ? dti : __logf(1.f + __expf(dti));
        const size_t idx = (size_t)(b * 9 + s) * 512 + c;
        const float xv = xcy[idx];
        const float dtx = dt * xv;
        float acc = 0.f;
        if (chain) {
            const float e1 = __expf(dt * a1);
            float en = 1.f;
            #pragma unroll
            for (int n = 0; n < 16; ++n) {
                en *= e1;
                hst[n] = fmaf(hst[n], en, dtx * xb[16 + n]);
                acc = fmaf(hst[n], xb[32 + n], acc);
            }
        } else {
            #pragma unroll
            for (int n = 0; n < 16; ++n) {
                hst[n] = fmaf(hst[n], __expf(dt * Ar[n]), dtx * xb[16 + n]);
                acc = fmaf(hst[n], xb[32 + n], acc);
            }
        }
        xcy[idx] = acc + Dc * xv;
    }
}

// ---------------- final head: (nr,32) -> (nb,9) -> out[b0+b] ---------------
__global__ __launch_bounds__(256) void head_kernel(
    const float* __restrict__ t32, const float* __restrict__ w2b,
    const float* __restrict__ b2b, const float* __restrict__ w3a,
    const float* __restrict__ b3a, const float* __restrict__ w3b,
    const float* __restrict__ b3b, float* __restrict__ out, int b0, int nb)
{
    int b = blockIdx.x * 256 + threadIdx.x;
    if (b >= nb) return;
    float o9[9];
    #pragma unroll
    for (int s = 0; s < 9; ++s) {
        const float* r = t32 + (size_t)(b * 9 + s) * 32;
        float acc = b2b[0];
        #pragma unroll
        for (int k = 0; k < 32; ++k) acc = fmaf(r[k], w2b[k], acc);
        o9[s] = acc;
    }
    float accout = b3b[0];
    #pragma unroll
    for (int j = 0; j < 9; ++j) {
        float rj = b3a[j];
        #pragma unroll
        for (int s = 0; s < 9; ++s) rj = fmaf(o9[s], w3a[j * 9 + s], rj);
        rj = fmaxf(rj, 0.f);
        accout = fmaf(rj, w3b[j], accout);
    }
    out[b0 + b] = accout;
}

// ---------------------------------------------------------------------------
extern "C" void kernel_launch(void* const* d_in, const int* in_sizes, int n_in,
                              void* d_out, int out_size, void* d_ws, size_t ws_size,
                              hipStream_t stream)
{
    const float* x          = (const float*)d_in[0];
    const float* w1         = (const float*)d_in[1];
    const float* b1         = (const float*)d_in[2];
    const float* attn_in_w  = (const float*)d_in[3];
    const float* attn_in_b  = (const float*)d_in[4];
    const float* attn_out_w = (const float*)d_in[5];
    const float* attn_out_b = (const float*)d_in[6];
    const float* ln1_g      = (const float*)d_in[7];
    const float* ln1_b      = (const float*)d_in[8];
    const float* ffw_w1     = (const float*)d_in[9];
    const float* ffw_b1     = (const float*)d_in[10];
    const float* ffw_w2     = (const float*)d_in[11];
    const float* ffw_b2     = (const float*)d_in[12];
    const float* ln2_g      = (const float*)d_in[13];
    const float* ln2_b      = (const float*)d_in[14];
    const float* in_proj_w  = (const float*)d_in[15];
    const float* conv_w     = (const float*)d_in[16];
    const float* conv_b     = (const float*)d_in[17];
    const float* x_proj_w   = (const float*)d_in[18];
    const float* dt_proj_w  = (const float*)d_in[19];
    const float* dt_proj_b  = (const float*)d_in[20];
    const float* A_log      = (const float*)d_in[21];
    const float* Dp         = (const float*)d_in[22];
    const float* out_proj_w = (const float*)d_in[23];
    const float* w2a        = (const float*)d_in[24];
    const float* b2a        = (const float*)d_in[25];
    const float* w2b        = (const float*)d_in[26];
    const float* b2b        = (const float*)d_in[27];
    const float* w3a        = (const float*)d_in[28];
    const float* b3a        = (const float*)d_in[29];
    const float* w3b        = (const float*)d_in[30];
    const float* b3b        = (const float*)d_in[31];
    float* out = (float*)d_out;

    // ---- weight bf16 arena + adaptive chunking ----------------------------
    const size_t WB_FLOATS = 589824;          // 1179648 ushorts
    const size_t PER_ROW = 1792;
    int nchunks = 1;
    while (nchunks < 32 &&
           (WB_FLOATS + (size_t)(BATCH / nchunks) * 9 * PER_ROW) * sizeof(float) > ws_size)
        nchunks <<= 1;
    const int nb = BATCH / nchunks;
    const int nr = nb * 9;
    const size_t CAPR = (size_t)nr;

    ushort* WB = (ushort*)d_ws;
    float*  AR = (float*)d_ws + WB_FLOATS;

    ushort* wb_attn_in  = WB;             // +i*196608
    ushort* wb_attn_out = WB + 393216;    // +i*65536
    ushort* wb_ffw1     = WB + 524288;    // +i*65536
    ushort* wb_ffw2     = WB + 655360;    // +i*65536
    ushort* wb_inproj_x = WB + 786432;
    ushort* wb_inproj_z = WB + 917504;
    ushort* wb_outproj  = WB + 1048576;

    // one-shot weight conversion (same every call -> graph-safe)
    hipLaunchKernelGGL(convw_kernel, dim3(1179648 / 256), dim3(256), 0, stream,
                       attn_in_w, attn_out_w, ffw_w1, ffw_w2, in_proj_w,
                       out_proj_w, WB);

    auto gemm = [&](const float* A, const float* W, const float* bias, float* C,
                    int M, int N, int K, int lda, int act) {
        dim3 grid((N + 63) / 64, (M + 63) / 64);
        hipLaunchKernelGGL(sgemm_kernel, grid, dim3(256), 0, stream,
                           A, W, bias, C, M, N, K, lda, act);
    };
    auto mgemm = [&](const ushort* A, const ushort* W, const float* bias,
                     float* Cf, ushort* Cb, const float* yin,
                     int M, int N, int K, int lda, int act, int outmode) {
        dim3 grid(M / 128, N / 128);
        hipLaunchKernelGGL(mgemm_kernel, grid, dim3(256), 0, stream,
                           A, W, bias, Cf, Cb, yin, M, N, K, lda, act, outmode);
    };

    for (int ck = 0; ck < nchunks; ++ck) {
        const int b0 = ck * nb;
        const int r0 = b0 * 9;

        float*  h    = AR;                           // (256) ; later h2
        ushort* hbf  = (ushort*)(AR + CAPR * 256);   // (128fl) lda 256
        float*  aux  = AR + CAPR * 384;              // (128fl): ao_bf | xdb | t32
        ushort* aobf = (ushort*)aux;                 // lda 256
        float*  big  = AR + CAPR * 512;              // (768)
        float*  qkv  = big;                          // lda 768
        float*  aa   = big;                          // lda 256 (qkv dead)
        ushort* f1bf = (ushort*)(big + CAPR * 256);  // lda 256
        float*  f2   = big + CAPR * 384;             // lda 256
        float*  xm   = big;                          // lda 512 (mamba)
        ushort* ybf  = (ushort*)(big + CAPR * 512);  // lda 512 (xm-free zone)
        float*  xc   = AR + CAPR * 1280;             // (512) xc then y in place
        float*  xdb  = aux;                          // lda 48 (mamba)
        float*  h2   = h;
        float*  t32  = aux;                          // lda 32

        hipLaunchKernelGGL(embed_kernel, dim3((nr * 256 + 255) / 256), dim3(256),
                           0, stream, x, w1, b1, h, hbf, r0, nr);

        for (int i = 0; i < 2; ++i) {
            mgemm(hbf, wb_attn_in + (size_t)i * 196608, attn_in_b + i * 768,
                  qkv, nullptr, nullptr, nr, 768, 256, 256, 0, 0);
            hipLaunchKernelGGL(attn_kernel, dim3(nb * 2), dim3(128), 0, stream,
                               qkv, aobf, nb);
            mgemm(aobf, wb_attn_out + (size_t)i * 65536, attn_out_b + i * 256,
                  aa, nullptr, nullptr, nr, 256, 256, 256, 0, 0);
            hipLaunchKernelGGL(ln_add_kernel, dim3((nr + 3) / 4), dim3(256), 0, stream,
                               h, aa, ln1_g + i * 256, ln1_b + i * 256, h, hbf, nr);
            mgemm(hbf, wb_ffw1 + (size_t)i * 65536, ffw_b1 + i * 256,
                  nullptr, f1bf, nullptr, nr, 256, 256, 256, 1, 1);
            mgemm(f1bf, wb_ffw2 + (size_t)i * 65536, ffw_b2 + i * 256,
                  f2, nullptr, nullptr, nr, 256, 256, 256, 0, 0);
            hipLaunchKernelGGL(ln_add_kernel, dim3((nr + 3) / 4), dim3(256), 0, stream,
                               h, f2, ln2_g + i * 256, ln2_b + i * 256, h, hbf, nr);
        }

        // ---- Mamba block ----
        mgemm(hbf, wb_inproj_x, nullptr, xm, nullptr, nullptr,
              nr, 512, 256, 256, 0, 0);
        hipLaunchKernelGGL(conv_silu_kernel, dim3((nr * 512 + 255) / 256), dim3(256),
                           0, stream, xm, conv_w, conv_b, xc, nr);
        gemm(xc, x_proj_w, nullptr, xdb, nr, 48, 512, 512, 0);
        hipLaunchKernelGGL(scan_kernel, dim3(nb), dim3(512), 0, stream,
                           xc, xdb, dt_proj_w, dt_proj_b, A_log, Dp);
        // z-GEMM with fused silu-gate: ybf = bf16(y * z*sig(z))
        mgemm(hbf, wb_inproj_z, nullptr, nullptr, ybf, xc,
              nr, 512, 256, 256, 0, 2);
        mgemm(ybf, wb_outproj, nullptr, h2, nullptr, nullptr,
              nr, 256, 512, 512, 0, 0);
        gemm(h2, w2a, b2a, t32, nr, 32, 256, 256, 0);
        hipLaunchKernelGGL(head_kernel, dim3((nb + 255) / 256), dim3(256), 0, stream,
                           t32, w2b, b2b, w3a, b3a, w3b, b3b, out, b0, nb);
    }
}